// Round 1
// baseline (490.319 us; speedup 1.0000x reference)
//
#include <hip/hip_runtime.h>
#include <stdint.h>
#include <stddef.h>

// ---------------------------------------------------------------------------
// MultiHeadAttention: x[4,2048,1024] -> out
//   q = x@Wq+bq ; k = x@Wk+bk ; v = x@Wv+bv   (per-head Dh=64, H=16)
//   attn = softmax(q k^T / 8) v ; out = attn_flat @ Wo + bo
// Internal compute: bf16 MFMA (v_mfma_f32_16x16x32_bf16), fp32 accumulate.
// I/O dtype (fp32 vs bf16) detected on-device from Wq bit patterns.
//
// R1 change vs 536us baseline: GEMM staging switched from reg-staged
// ds_write_b128 to __builtin_amdgcn_global_load_lds width=16 (m97 pattern,
// +69% on the 128^2/BK=32/2-barrier structure). To make A always-bf16, x is
// pre-converted once by norm_x into d_out (dead region until attention).
// LDS layouts, frag reads, epilogues, and attn_fused are bit-identical to
// the verified baseline.
// ---------------------------------------------------------------------------

typedef __attribute__((ext_vector_type(8))) short          s16x8;  // mfma A/B frag
typedef __attribute__((ext_vector_type(8))) unsigned short u16x8;  // 16B data movement
typedef __attribute__((ext_vector_type(4))) float          f32x4;  // mfma C/D frag

#define DMODEL 1024
#define SEQ    2048
#define NHEAD  16
#define DHEAD  64
#define NTOK   8192
#define SCALE  0.125f

#define MFMA_B16(a, b, c) __builtin_amdgcn_mfma_f32_16x16x32_bf16((a), (b), (c), 0, 0, 0)

__device__ __forceinline__ float bf2f(unsigned short u) {
  union { unsigned int i; float f; } v; v.i = ((unsigned int)u) << 16; return v.f;
}
__device__ __forceinline__ unsigned short f2bf(float f) {
  union { float f; unsigned int i; } v; v.f = f;
  unsigned int r = v.i + 0x7FFFu + ((v.i >> 16) & 1u);  // RNE
  return (unsigned short)(r >> 16);
}

// async global->LDS, 16B per lane. LDS dest is wave-uniform base + lane*16.
__device__ __forceinline__ void gld16(const unsigned short* g, unsigned short* l) {
  __builtin_amdgcn_global_load_lds(
      (const __attribute__((address_space(1))) void*)g,
      (__attribute__((address_space(3))) void*)l, 16, 0, 0);
}

// ---------------------------------------------------------------------------
// Detect input dtype. Wq is uniform(-1/32, 1/32):
//  - true bf16 data: no u16 word has |bf16(word)| >= 1.0
//  - fp32 data read as u16: ~25% of words decode to |bf16| >= 1.0.
// flag=1 -> inputs are fp32.
// ---------------------------------------------------------------------------
__global__ void detect_fp32(const unsigned short* __restrict__ w, int* __restrict__ flag) {
  __shared__ int cnt;
  if (threadIdx.x == 0) cnt = 0;
  __syncthreads();
  int local = 0;
  for (int i = threadIdx.x; i < 8192; i += 256) {
    const unsigned short v = w[i];
    if ((v & 0x7F80u) >= 0x3F80u) local++;  // |bf16| >= 1.0
  }
  atomicAdd(&cnt, local);
  __syncthreads();
  if (threadIdx.x == 0) *flag = (cnt >= 128) ? 1 : 0;
}

// ---------------------------------------------------------------------------
// Normalize a small vector (bias) to bf16, flag-aware. n multiple of 256.
// ---------------------------------------------------------------------------
__global__ void norm_vec(const void* __restrict__ src, unsigned short* __restrict__ dst,
                         int n, const int* __restrict__ flag) {
  const int fl = *flag;
  const int i = blockIdx.x * 256 + threadIdx.x;
  if (i < n) {
    dst[i] = fl ? f2bf(((const float*)src)[i]) : ((const unsigned short*)src)[i];
  }
}

// ---------------------------------------------------------------------------
// norm_x: x (fp32 or bf16 per flag) -> bf16, 8M elems, 8 per thread.
// ---------------------------------------------------------------------------
__global__ __launch_bounds__(256) void norm_x(const void* __restrict__ src,
                                              unsigned short* __restrict__ dst,
                                              const int* __restrict__ flag) {
  const int fl = *flag;
  const size_t i = ((size_t)blockIdx.x * 256 + threadIdx.x) * 8;
  if (fl) {
    const float* s = (const float*)src + i;
    u16x8 o;
#pragma unroll
    for (int j = 0; j < 8; ++j) o[j] = f2bf(s[j]);
    *(u16x8*)(dst + i) = o;
  } else {
    *(u16x8*)(dst + i) = *(const u16x8*)((const unsigned short*)src + i);
  }
}

// ---------------------------------------------------------------------------
// Transpose 1024x1024 to bf16: out[n][k] = (bf16)in[k][n], flag-aware load.
// block (64,4), grid (16,16)
// ---------------------------------------------------------------------------
__global__ __launch_bounds__(256) void transpose1024(const void* __restrict__ in,
                                                     unsigned short* __restrict__ out,
                                                     const int* __restrict__ flag) {
  __shared__ unsigned short tile[64][65];
  const int fl = *flag;
  const int tx = threadIdx.x;  // 0..63
  const int ty = threadIdx.y;  // 0..3
  const int bx = blockIdx.x * 64;
  const int by = blockIdx.y * 64;
  const float* inf = (const float*)in;
  const unsigned short* inu = (const unsigned short*)in;
#pragma unroll
  for (int i = 0; i < 16; ++i) {
    const int r = i * 4 + ty;
    const size_t idx = (size_t)(by + r) * DMODEL + bx + tx;
    tile[r][tx] = fl ? f2bf(inf[idx]) : inu[idx];
  }
  __syncthreads();
#pragma unroll
  for (int i = 0; i < 16; ++i) {
    const int r = i * 4 + ty;
    out[(size_t)(bx + r) * DMODEL + by + tx] = tile[tx][r];
  }
}

// ---------------------------------------------------------------------------
// GEMM: C[m][n] = sum_k A[m][k] * Bt[n][k] + bias[n]   (fp32 acc)
// BM=BN=128, BK=32; 256 threads = 4 waves, each wave a 64x64 quadrant.
// A is ALWAYS bf16 now (Xb for MODE 1, attn-out for MODE 0).
// Staging: 4x global_load_lds width=16 per thread per K-step (m97 pattern).
// LDS layout [row][k] row-major stride 32 -- identical bytes to baseline, so
// frag reads and epilogue are unchanged/verified.
// MODE 1: fused QKV (N=3072, Bt = WqT|WkT|WvT); scatter bf16 to Q/K/V.
// MODE 0: writes fp32 to Cf.
// ---------------------------------------------------------------------------
template <int MODE>
__global__ __launch_bounds__(256) void gemm_bt(const unsigned short* __restrict__ A,
                                               const unsigned short* __restrict__ Bt,
                                               const unsigned short* __restrict__ bias0,
                                               const unsigned short* __restrict__ bias1,
                                               const unsigned short* __restrict__ bias2,
                                               unsigned short* __restrict__ C0,
                                               unsigned short* __restrict__ C1,
                                               unsigned short* __restrict__ C2,
                                               float* __restrict__ Cf) {
  __shared__ __align__(16) unsigned short As[128 * 32];
  __shared__ __align__(16) unsigned short Bs[128 * 32];

  const int t = threadIdx.x;
  const int wv = t >> 6;
  const int lane = t & 63;
  const int q4 = lane >> 4;   // 0..3
  const int c  = lane & 15;   // 0..15
  const int wm = wv >> 1;     // 0..1
  const int wn = wv & 1;      // 0..1
  const int m0 = blockIdx.x * 128;
  const int n0 = blockIdx.y * 128;

  f32x4 acc[4][4];
#pragma unroll
  for (int i = 0; i < 4; ++i)
#pragma unroll
    for (int j = 0; j < 4; ++j) acc[i][j] = (f32x4){0.f, 0.f, 0.f, 0.f};

  // Staging map: LDS 16B chunk ch in [0,512) covers As elems ch*8..ch*8+7,
  // i.e. tile row ch>>2, k-chunk (ch&3)*8. Wave wv handles chunks
  // wv*128 + lane (call 0) and + 64 (call 1); dest = linear lane order.
  const int ch0 = wv * 128 + lane;
  const int ch1 = ch0 + 64;
  const unsigned short* Ag0 = A  + (size_t)(m0 + (ch0 >> 2)) * DMODEL + (ch0 & 3) * 8;
  const unsigned short* Ag1 = A  + (size_t)(m0 + (ch1 >> 2)) * DMODEL + (ch1 & 3) * 8;
  const unsigned short* Bg0 = Bt + (size_t)(n0 + (ch0 >> 2)) * DMODEL + (ch0 & 3) * 8;
  const unsigned short* Bg1 = Bt + (size_t)(n0 + (ch1 >> 2)) * DMODEL + (ch1 & 3) * 8;
  unsigned short* Al0 = As + (wv * 2 + 0) * 512;  // wave-uniform LDS bases
  unsigned short* Al1 = As + (wv * 2 + 1) * 512;
  unsigned short* Bl0 = Bs + (wv * 2 + 0) * 512;
  unsigned short* Bl1 = Bs + (wv * 2 + 1) * 512;

  for (int k0 = 0; k0 < DMODEL; k0 += 32) {
    gld16(Ag0 + k0, Al0);
    gld16(Ag1 + k0, Al1);
    gld16(Bg0 + k0, Bl0);
    gld16(Bg1 + k0, Bl1);
    __syncthreads();  // drains vmcnt -> staged tile visible to all waves

    s16x8 af[4], bfr[4];
#pragma unroll
    for (int i = 0; i < 4; ++i)
      af[i] = *(const s16x8*)(As + (wm * 64 + i * 16 + c) * 32 + q4 * 8);
#pragma unroll
    for (int j = 0; j < 4; ++j)
      bfr[j] = *(const s16x8*)(Bs + (wn * 64 + j * 16 + c) * 32 + q4 * 8);
#pragma unroll
    for (int i = 0; i < 4; ++i)
#pragma unroll
      for (int j = 0; j < 4; ++j) acc[i][j] = MFMA_B16(af[i], bfr[j], acc[i][j]);
    __syncthreads();  // all frag reads done before next iter's DMA overwrites
  }

  // epilogue: C/D layout row = q4*4+reg, col = c
#pragma unroll
  for (int j = 0; j < 4; ++j) {
    const int n = n0 + wn * 64 + j * 16 + c;
    float bval;
    if (MODE == 0) {
      bval = bf2f(bias0[n]);
    } else {
      const int r = n >> 10, nn = n & 1023;
      const unsigned short* bp = (r == 0) ? bias0 : (r == 1 ? bias1 : bias2);
      bval = bf2f(bp[nn]);
    }
#pragma unroll
    for (int i = 0; i < 4; ++i) {
#pragma unroll
      for (int rg = 0; rg < 4; ++rg) {
        const int m = m0 + wm * 64 + i * 16 + q4 * 4 + rg;
        const float oval = acc[i][j][rg] + bval;
        if (MODE == 0) {
          Cf[(size_t)m * DMODEL + n] = oval;  // fp32 scratch; copyout converts
        } else {
          const int r = n >> 10;
          const int d = n & 1023;
          const int h = d >> 6, dh = d & 63;
          const int b = m >> 11, s = m & 2047;
          unsigned short* Cp = (r == 0) ? C0 : (r == 1 ? C1 : C2);
          Cp[((((size_t)b * NHEAD + h) * SEQ + s) << 6) + dh] = f2bf(oval);
        }
      }
    }
  }
}

// ---------------------------------------------------------------------------
// copyout: d_out <- X (fp32), stored as fp32 or bf16 per flag.
// ---------------------------------------------------------------------------
__global__ void copyout(const float* __restrict__ X, void* __restrict__ out,
                        const int* __restrict__ flag) {
  const int fl = *flag;
  const size_t i = (size_t)blockIdx.x * 1024 + threadIdx.x * 4;
#pragma unroll
  for (int j = 0; j < 4; ++j) {
    const float v = X[i + j];
    if (fl) ((float*)out)[i + j] = v;
    else    ((unsigned short*)out)[i + j] = f2bf(v);
  }
}

// ---------------------------------------------------------------------------
// Flash attention, full (non-causal). One block = (bh, 128 q rows), 4 waves;
// wave owns 32 q rows (2 mfma m-tiles). Per iter: 64 keys.
// LDS layouts are 2 panels of [rows][32] bf16 (64B row stride). P round-trips
// through LDS to convert C-layout -> A-operand layout (verified m120 pattern).
// UNCHANGED from the 536us baseline.
// ---------------------------------------------------------------------------
__global__ __launch_bounds__(256) void attn_fused(const unsigned short* __restrict__ Qg,
                                                  const unsigned short* __restrict__ Kg,
                                                  const unsigned short* __restrict__ Vg,
                                                  unsigned short* __restrict__ Of) {
  __shared__ __align__(16) unsigned short Qs[128 * 64];  // 2 panels [128][32] by dh
  __shared__ __align__(16) unsigned short Ks[64 * 64];   // 2 panels [64][32] by dh
  __shared__ __align__(16) unsigned short Vt[64 * 64];   // V^T: 2 panels [dh:64][32] by s
  __shared__ __align__(16) unsigned short Ps[128 * 64];  // 4 wave strips

  const int t = threadIdx.x;
  const int wv = t >> 6;
  const int lane = t & 63;
  const int q4 = lane >> 4;
  const int c  = lane & 15;
  const int bh = blockIdx.y;
  const int q0 = blockIdx.x * 128;

  const unsigned short* Qb = Qg + ((size_t)bh * SEQ + q0) * DHEAD;
  const unsigned short* Kb = Kg + (size_t)bh * SEQ * DHEAD;
  const unsigned short* Vb = Vg + (size_t)bh * SEQ * DHEAD;

  // ---- stage Q (128x64) once ----
  {
    const int row = t >> 1;
    const int half = t & 1;  // dh panel
    const unsigned short* src = Qb + row * DHEAD + half * 32;
    unsigned short* dst = Qs + half * 4096 + row * 32;
#pragma unroll
    for (int j = 0; j < 4; ++j) *(u16x8*)(dst + j * 8) = *(const u16x8*)(src + j * 8);
  }
  __syncthreads();

  // Q frags live in registers for the whole loop
  s16x8 qf[2][2];
#pragma unroll
  for (int mi = 0; mi < 2; ++mi)
#pragma unroll
    for (int kb = 0; kb < 2; ++kb)
      qf[mi][kb] = *(const s16x8*)(Qs + kb * 4096 + (wv * 32 + mi * 16 + c) * 32 + q4 * 8);

  f32x4 acco[2][4];
#pragma unroll
  for (int mi = 0; mi < 2; ++mi)
#pragma unroll
    for (int dt = 0; dt < 4; ++dt) acco[mi][dt] = (f32x4){0.f, 0.f, 0.f, 0.f};
  float mrun[2][4], lrun[2][4];
#pragma unroll
  for (int mi = 0; mi < 2; ++mi)
#pragma unroll
    for (int rg = 0; rg < 4; ++rg) { mrun[mi][rg] = -1e30f; lrun[mi][rg] = 0.f; }

  const int krow = t >> 2;          // K staging: 0..63
  const int kch  = t & 3;           // 16-elem chunk
  const int vr   = t & 63;          // V staging: source row
  const int dh0  = (t >> 6) * 16;   // V staging: dh chunk per wave

  for (int kt = 0; kt < SEQ / 64; ++kt) {
    // global -> regs
    const unsigned short* ksrc = Kb + (size_t)(kt * 64 + krow) * DHEAD + kch * 16;
    u16x8 kv0 = *(const u16x8*)(ksrc);
    u16x8 kv1 = *(const u16x8*)(ksrc + 8);
    const unsigned short* vsrc = Vb + (size_t)(kt * 64 + vr) * DHEAD + dh0;
    u16x8 vv0 = *(const u16x8*)(vsrc);
    u16x8 vv1 = *(const u16x8*)(vsrc + 8);

    __syncthreads();  // prior iter's Ks/Vt reads done
    {
      unsigned short* kdst = Ks + (kch >> 1) * 2048 + krow * 32 + (kch & 1) * 16;
      *(u16x8*)(kdst) = kv0;
      *(u16x8*)(kdst + 8) = kv1;
      unsigned short* vdst = Vt + (vr >> 5) * 2048 + (vr & 31);
#pragma unroll
      for (int j = 0; j < 8; ++j) vdst[(dh0 + j) * 32] = vv0[j];
#pragma unroll
      for (int j = 0; j < 8; ++j) vdst[(dh0 + 8 + j) * 32] = vv1[j];
    }
    __syncthreads();

    // ---- S = Q K^T ----
    f32x4 accs[2][4];
#pragma unroll
    for (int mi = 0; mi < 2; ++mi)
#pragma unroll
      for (int nt = 0; nt < 4; ++nt) accs[mi][nt] = (f32x4){0.f, 0.f, 0.f, 0.f};
    s16x8 kf[2][4];
#pragma unroll
    for (int kb = 0; kb < 2; ++kb)
#pragma unroll
      for (int nt = 0; nt < 4; ++nt)
        kf[kb][nt] = *(const s16x8*)(Ks + kb * 2048 + (nt * 16 + c) * 32 + q4 * 8);
#pragma unroll
    for (int mi = 0; mi < 2; ++mi)
#pragma unroll
      for (int nt = 0; nt < 4; ++nt) {
        accs[mi][nt] = MFMA_B16(qf[mi][0], kf[0][nt], accs[mi][nt]);
        accs[mi][nt] = MFMA_B16(qf[mi][1], kf[1][nt], accs[mi][nt]);
      }

    // ---- online softmax (rows = q4*4+rg; 16-lane groups share a row) ----
#pragma unroll
    for (int mi = 0; mi < 2; ++mi) {
#pragma unroll
      for (int rg = 0; rg < 4; ++rg) {
        float vmax = -1e30f;
#pragma unroll
        for (int nt = 0; nt < 4; ++nt) {
          accs[mi][nt][rg] *= SCALE;
          vmax = fmaxf(vmax, accs[mi][nt][rg]);
        }
        vmax = fmaxf(vmax, __shfl_xor(vmax, 1));
        vmax = fmaxf(vmax, __shfl_xor(vmax, 2));
        vmax = fmaxf(vmax, __shfl_xor(vmax, 4));
        vmax = fmaxf(vmax, __shfl_xor(vmax, 8));
        const float mnew = fmaxf(mrun[mi][rg], vmax);
        const float alpha = __expf(mrun[mi][rg] - mnew);
        mrun[mi][rg] = mnew;
        float rsum = 0.f;
#pragma unroll
        for (int nt = 0; nt < 4; ++nt) {
          const float p = __expf(accs[mi][nt][rg] - mnew);
          accs[mi][nt][rg] = p;
          rsum += p;
        }
        rsum += __shfl_xor(rsum, 1);
        rsum += __shfl_xor(rsum, 2);
        rsum += __shfl_xor(rsum, 4);
        rsum += __shfl_xor(rsum, 8);
        lrun[mi][rg] = lrun[mi][rg] * alpha + rsum;
#pragma unroll
        for (int dt = 0; dt < 4; ++dt) acco[mi][dt][rg] *= alpha;
      }
    }

    // ---- P (bf16) -> LDS strip (C-layout write), read back as A-frags ----
    unsigned short* pw = Ps + wv * 2048;
#pragma unroll
    for (int mi = 0; mi < 2; ++mi)
#pragma unroll
      for (int nt = 0; nt < 4; ++nt)
#pragma unroll
        for (int rg = 0; rg < 4; ++rg)
          pw[(nt >> 1) * 1024 + (mi * 16 + q4 * 4 + rg) * 32 + (nt & 1) * 16 + c] =
              f2bf(accs[mi][nt][rg]);

    s16x8 vf[2][4], pf[2][2];
#pragma unroll
    for (int kb = 0; kb < 2; ++kb) {
#pragma unroll
      for (int dt = 0; dt < 4; ++dt)
        vf[kb][dt] = *(const s16x8*)(Vt + kb * 2048 + (dt * 16 + c) * 32 + q4 * 8);
#pragma unroll
      for (int mi = 0; mi < 2; ++mi)
        pf[mi][kb] = *(const s16x8*)(pw + kb * 1024 + (mi * 16 + c) * 32 + q4 * 8);
    }
#pragma unroll
    for (int mi = 0; mi < 2; ++mi)
#pragma unroll
      for (int dt = 0; dt < 4; ++dt) {
        acco[mi][dt] = MFMA_B16(pf[mi][0], vf[0][dt], acco[mi][dt]);
        acco[mi][dt] = MFMA_B16(pf[mi][1], vf[1][dt], acco[mi][dt]);
      }
  }

  // ---- epilogue: O_flat[token][h*64+dh] (bf16 into d_out scratch) ----
  const int b = bh >> 4;
  const int h = bh & 15;
#pragma unroll
  for (int mi = 0; mi < 2; ++mi)
#pragma unroll
    for (int rg = 0; rg < 4; ++rg) {
      const int s = q0 + wv * 32 + mi * 16 + q4 * 4 + rg;
      const float inv = 1.0f / lrun[mi][rg];
      unsigned short* orow = Of + ((size_t)b * SEQ + s) * DMODEL + h * DHEAD;
#pragma unroll
      for (int dt = 0; dt < 4; ++dt) orow[dt * 16 + c] = f2bf(acco[mi][dt][rg] * inv);
    }
}

// ---------------------------------------------------------------------------
extern "C" void kernel_launch(void* const* d_in, const int* in_sizes, int n_in,
                              void* d_out, int out_size, void* d_ws, size_t ws_size,
                              hipStream_t stream) {
  const void* x  = d_in[0];
  const void* Wq = d_in[1];
  const void* bq = d_in[2];
  const void* Wk = d_in[3];
  const void* bk = d_in[4];
  const void* Wv = d_in[5];
  const void* bv = d_in[6];
  const void* Wo = d_in[7];
  const void* bo = d_in[8];

  unsigned short* ws = (unsigned short*)d_ws;
  const size_t M1 = (size_t)DMODEL * DMODEL;   // 1M elems (one weight)
  const size_t MQ = (size_t)NTOK * DMODEL;     // 8M elems (one activation)

  // Layout (~56MB): QKV | W^T x4 | biases | flag.  X (fp32 out scratch, 32MB)
  // aliases Kw+Vw (dead after attention).
  // d_out scratch timeline: Xb (bf16 x) -> dead after gemm<1> -> Ob (attn out)
  // -> dead after gemm<0> -> final output via copyout.  d_out >= 16MB always.
  unsigned short* Qw  = ws;
  unsigned short* Kw  = Qw + MQ;
  unsigned short* Vw  = Kw + MQ;
  unsigned short* WqT = Vw + MQ;
  unsigned short* WkT = WqT + M1;
  unsigned short* WvT = WkT + M1;
  unsigned short* WoT = WvT + M1;
  unsigned short* bqn = WoT + M1;
  unsigned short* bkn = bqn + 1024;
  unsigned short* bvn = bkn + 1024;
  unsigned short* bon = bvn + 1024;
  int*            flg = (int*)(bon + 1024);
  float*          X   = (float*)Kw;             // 32MB fp32, post-attention only
  unsigned short* Xb  = (unsigned short*)d_out; // bf16 x (pre-QKV only)
  unsigned short* Ob  = (unsigned short*)d_out; // bf16 attention-out scratch

  detect_fp32<<<1, 256, 0, stream>>>((const unsigned short*)Wq, flg);

  norm_vec<<<4, 256, 0, stream>>>(bq, bqn, 1024, flg);
  norm_vec<<<4, 256, 0, stream>>>(bk, bkn, 1024, flg);
  norm_vec<<<4, 256, 0, stream>>>(bv, bvn, 1024, flg);
  norm_vec<<<4, 256, 0, stream>>>(bo, bon, 1024, flg);

  dim3 tb(64, 4);
  transpose1024<<<dim3(16, 16), tb, 0, stream>>>(Wq, WqT, flg);
  transpose1024<<<dim3(16, 16), tb, 0, stream>>>(Wk, WkT, flg);
  transpose1024<<<dim3(16, 16), tb, 0, stream>>>(Wv, WvT, flg);
  transpose1024<<<dim3(16, 16), tb, 0, stream>>>(Wo, WoT, flg);

  norm_x<<<4096, 256, 0, stream>>>(x, Xb, flg);

  gemm_bt<1><<<dim3(64, 24), 256, 0, stream>>>(Xb, WqT, bqn, bkn, bvn,
                                               Qw, Kw, Vw, nullptr);
  attn_fused<<<dim3(16, 64), 256, 0, stream>>>(Qw, Kw, Vw, Ob);
  gemm_bt<0><<<dim3(64, 8), 256, 0, stream>>>(Ob, WoT, bon, bon, bon,
                                              nullptr, nullptr, nullptr, X);
  copyout<<<8192, 256, 0, stream>>>(X, d_out, flg);
}